// Round 1
// baseline (153.740 us; speedup 1.0000x reference)
//
#include <hip/hip_runtime.h>

// LFR frame stacking: x (B=64, T=4096, D=80) f32, lens (B,) i32
// out (B, NF=683, M*D=560) f32 ++ new_len (B,) f32
//
// Derived semantics (verified, absmax 0.0): T_all_max = 4099 fixed (lens[0]=T),
// NF = (4099-7)/6+1 = 683. Gather index for output position t=6f+m:
//   src = 0 if t<3; t-3 if t<3+lens[b]; else T-1.
//
// Round 1: inferred lfr dispatch ~37.6us (152.2 total - 2x57.3 fill) vs ~22-29us
// mixed-stream roofline. Changes: (a) nontemporal stores — output is write-once,
// bypass L2 so x stays resident for frame-overlap / clamp-broadcast re-reads;
// (b) 2-way unroll at +256 stride — perfect per-instruction coalescing kept,
// 2x MLP per wave, half the blocks.

typedef float __attribute__((ext_vector_type(4))) f32x4;

constexpr int B    = 64;
constexpr int T    = 4096;
constexpr int D    = 80;
constexpr int NF   = 683;
constexpr int M    = 7;
constexpr int N    = 6;
constexpr int LEFT = 3;

constexpr int D4     = D / 4;         // 20 float4 per frame
constexpr int ROW4   = M * D4;        // 140 float4 per output row
constexpr int TOTAL4 = B * NF * ROW4; // 6,119,680 float4 total

__device__ __forceinline__ int src_index(int idx, const int* __restrict__ lens) {
    int row = idx / ROW4;          // (b, f) flat
    int r   = idx - row * ROW4;    // position within row, [0,140)
    int b   = row / NF;
    int f   = row - b * NF;
    int m   = r / D4;              // which of M frames
    int d4  = r - m * D4;          // float4 within frame
    int t   = f * N + m;           // gather position in padded time axis
    int L   = lens[b];
    int src = (t < LEFT) ? 0 : (t < LEFT + L) ? (t - LEFT) : (T - 1);
    return (b * T + src) * D4 + d4;
}

__global__ __launch_bounds__(256) void lfr_kernel(
    const f32x4* __restrict__ x,      // (B*T*D4) float4
    const int*   __restrict__ lens,   // (B,)
    f32x4*       __restrict__ out,    // (B*NF*ROW4) float4
    float*       __restrict__ new_len) // (B,)
{
    // fused tiny output: new_len
    if (blockIdx.x == 0 && threadIdx.x < B) {
        int L   = lens[threadIdx.x];
        int rem = L % N;
        int rp  = (rem == 1) ? 3 : (rem == 2) ? 2 : (rem == 3) ? 1 : 0;
        new_len[threadIdx.x] = (float)((LEFT + L + rp) / N);
    }

    int idx0 = blockIdx.x * 512 + (int)threadIdx.x;
    int idx1 = idx0 + 256;

    // TOTAL4 % 512 == 256, so idx0 is always in range for the launched grid;
    // only idx1 needs the guard (last block). Keep both guards — they cost
    // one s_cmp each and protect against future constant changes.
    bool ok0 = idx0 < TOTAL4;
    bool ok1 = idx1 < TOTAL4;

    f32x4 v0, v1;
    if (ok0) v0 = x[src_index(idx0, lens)];
    if (ok1) v1 = x[src_index(idx1, lens)];

    if (ok0) __builtin_nontemporal_store(v0, &out[idx0]);
    if (ok1) __builtin_nontemporal_store(v1, &out[idx1]);
}

extern "C" void kernel_launch(void* const* d_in, const int* in_sizes, int n_in,
                              void* d_out, int out_size, void* d_ws, size_t ws_size,
                              hipStream_t stream) {
    const f32x4* x    = (const f32x4*)d_in[0];
    const int*   lens = (const int*)d_in[1];
    float*       out  = (float*)d_out;
    float*       nl   = out + (size_t)B * NF * M * D; // new_len after main output

    int blocks = (TOTAL4 + 511) / 512; // 11,953
    lfr_kernel<<<blocks, 256, 0, stream>>>((const f32x4*)x, lens, (f32x4*)out, nl);
}